// Round 3
// baseline (178.348 us; speedup 1.0000x reference)
//
#include <hip/hip_runtime.h>

// MaxUnpool2D scatter formulation:
//   input_pool [B=8, H=128, W=128, C=64] f32
//   pool_mask  [B, H, W, C] i32 -- flat per-batch index (ho*WOUT + wo)*C + c
//   out        [B, 256, 256, C] f32
//
// One thread per input float4 (4 channels of one pooled pixel). Reads x/mask
// exactly once (nontemporal, no reuse), writes all 4 output vecs of its 2x2
// window exactly once. Zero-fill is fused: non-selected positions get 0.0f.
// Uses clang ext_vector_type (not HIP_vector_type) so nontemporal builtins
// accept the pointers.

#define Hdim  128
#define Wdim  128
#define Cdim  64
#define HOUT  256
#define WOUT  256
#define CV    (Cdim / 4)   // 16 vec4 per pixel

typedef float vf4 __attribute__((ext_vector_type(4)));
typedef int   vi4 __attribute__((ext_vector_type(4)));

__global__ __launch_bounds__(256) void maxunpool_scatter(
    const vf4* __restrict__ x,     // [B*H*W*CV]
    const vi4* __restrict__ mask,  // [B*H*W*CV]
    vf4*       __restrict__ out)   // [B*HOUT*WOUT*CV]
{
    unsigned int tid = blockIdx.x * blockDim.x + threadIdx.x;  // [b,h,w,c4]

    int c4 = tid & (CV - 1);
    unsigned int p = tid >> 4;      // (b*H + h)*W + w
    int w = p & (Wdim - 1);
    unsigned int q = p >> 7;
    int h = q & (Hdim - 1);
    int b = q >> 7;

    vi4 m = __builtin_nontemporal_load(&mask[tid]);
    vf4 v = __builtin_nontemporal_load(&x[tid]);

    int ho = h << 1;
    int wo = w << 1;

    // output vec index of window corner (b, ho, wo, c4)
    unsigned int o00 = ((unsigned int)(b * HOUT + ho) * WOUT + wo) * CV + c4;

    #pragma unroll
    for (int dh = 0; dh < 2; ++dh) {
        #pragma unroll
        for (int dw = 0; dw < 2; ++dw) {
            // expected flat mask value for this window position, channels c4*4..+3
            int base = ((ho + dh) * WOUT + (wo + dw)) * Cdim + (c4 << 2);
            vf4 r;
            r.x = (m.x == base + 0) ? v.x : 0.0f;
            r.y = (m.y == base + 1) ? v.y : 0.0f;
            r.z = (m.z == base + 2) ? v.z : 0.0f;
            r.w = (m.w == base + 3) ? v.w : 0.0f;
            unsigned int oidx = o00 + (unsigned int)(dh * WOUT + dw) * CV;
            __builtin_nontemporal_store(r, &out[oidx]);
        }
    }
}

extern "C" void kernel_launch(void* const* d_in, const int* in_sizes, int n_in,
                              void* d_out, int out_size, void* d_ws, size_t ws_size,
                              hipStream_t stream) {
    const vf4* x    = (const vf4*)d_in[0];
    const vi4* mask = (const vi4*)d_in[1];
    vf4*       out  = (vf4*)d_out;

    // in_sizes[0] = 8*128*128*64 = 8,388,608 elements -> /4 = 2,097,152 threads
    const int n_vec = in_sizes[0] / 4;
    const int block = 256;
    const int grid  = n_vec / block;  // 8192, exact

    maxunpool_scatter<<<grid, block, 0, stream>>>(x, mask, out);
}